// Round 10
// baseline (302.325 us; speedup 1.0000x reference)
//
#include <hip/hip_runtime.h>

// Problem constants
#define B_    32
#define CIN_  256
#define H_    64
#define W_    64
#define OH_   28
#define OW_   28
#define M_TOTAL 25088      // B*OH*OW
#define POSE_ELEMS 6422528 // B*32*OH*OW*8

typedef _Float16 f16;
typedef _Float16 f16x8 __attribute__((ext_vector_type(8)));
typedef _Float16 f16x4 __attribute__((ext_vector_type(4)));
typedef float    f32x4 __attribute__((ext_vector_type(4)));

#define GLD_LDS16(gp, lp) __builtin_amdgcn_global_load_lds( \
    (const __attribute__((address_space(1))) void*)(gp),    \
    (__attribute__((address_space(3))) void*)(lp), 16, 0, 0)

#define SBAR()    asm volatile("s_barrier" ::: "memory")
#define WAITVM0() asm volatile("s_waitcnt vmcnt(0)" ::: "memory")
#define WAITVM2() asm volatile("s_waitcnt vmcnt(2)" ::: "memory")

// ---------------------------------------------------------------------------
// Kernel 1: x [B,CIN,H,W] fp32 -> Xt [B,H,W,CIN] fp16  (float4 global loads)
// ---------------------------------------------------------------------------
__global__ __launch_bounds__(256) void xt_kernel(const float* __restrict__ x,
                                                 f16* __restrict__ Xt)
{
    __shared__ float tile[64 * 65];
    const int t  = threadIdx.x;
    const int c0 = blockIdx.x * 64;
    const int h  = blockIdx.y;
    const int b  = blockIdx.z;

    const float* src = x + (((long)(b * CIN_ + c0)) * H_ + h) * W_;
    const int w4 = (t & 15) * 4;   // float4 column
    const int cr = t >> 4;         // 16 rows per pass
#pragma unroll
    for (int it = 0; it < 4; ++it) {
        const int c = it * 16 + cr;
        const float4 v = *(const float4*)(src + (long)c * (H_ * W_) + w4);
        tile[c * 65 + w4 + 0] = v.x;
        tile[c * 65 + w4 + 1] = v.y;
        tile[c * 65 + w4 + 2] = v.z;
        tile[c * 65 + w4 + 3] = v.w;
    }
    __syncthreads();

    f16* dst = Xt + ((long)(b * H_ + h) * W_) * CIN_ + c0;
    const int wq = t >> 4, cq = t & 15;
#pragma unroll
    for (int it = 0; it < 4; ++it) {
        const int w2 = it * 16 + wq;
        f16x4 v;
        v[0] = (f16)tile[(cq * 4 + 0) * 65 + w2];
        v[1] = (f16)tile[(cq * 4 + 1) * 65 + w2];
        v[2] = (f16)tile[(cq * 4 + 2) * 65 + w2];
        v[3] = (f16)tile[(cq * 4 + 3) * 65 + w2];
        *(f16x4*)(dst + (long)w2 * CIN_ + cq * 4) = v;
    }
}

// ---------------------------------------------------------------------------
// Kernel 2: conv_w [COUT,CIN,9,9] fp32 -> Wt in MFMA-FRAGMENT order:
//   Wt[ks=khw*4+cb][n16][h][lane][e]  (f16), flat stride 16384 f16 per ks.
//   lane = lhi*16 + llo:  n = n16*16 + llo,  k_in64 = h*32 + lhi*8 + e.
// GEMM-side B-frag load becomes one coalesced global_load_dwordx4 per frag.
// ---------------------------------------------------------------------------
__global__ __launch_bounds__(256) void wt_kernel(const float* __restrict__ w,
                                                 f16* __restrict__ Wt)
{
    __shared__ float tile[64 * 81];
    const int t  = threadIdx.x;
    const int co = blockIdx.x >> 2;          // output channel n (0..255)
    const int cb = blockIdx.x & 3;           // cin block
    const float* src = w + ((long)co * 256 + cb * 64) * 81;
    for (int i = t; i < 64 * 81; i += 256) tile[i] = src[i];
    __syncthreads();

    const int n16 = co >> 4, llo = co & 15;
    for (int i = t; i < 648; i += 256) {     // 81 khw * 2 h * 4 lhi
        const int khw = i >> 3;
        const int rem = i & 7;
        const int h = rem >> 2, lhi = rem & 3;
        const int k0 = h * 32 + lhi * 8;
        f16x8 v;
#pragma unroll
        for (int e = 0; e < 8; ++e) v[e] = (f16)tile[(k0 + e) * 81 + khw];
        const long off = ((long)(khw * 4 + cb) * 2048 + n16 * 128 + h * 64 + lhi * 16 + llo) * 8;
        *(f16x8*)(Wt + off) = v;
    }
}

// ---------------------------------------------------------------------------
// Kernel 3: A-only-LDS 2-phase split-K implicit-GEMM (256x256, BK=64, 8 waves).
// B operand: per-wave register fragments loaded coalesced from frag-ordered Wt
// (L2-hot: each XCD's sk slice ~2.1MB). LDS holds only A (2 x 32KB dbuf).
// Per tile: S1{stage A-h0(t+1); VM2; SBAR; read afL; Q(0,0)+Q(0,1)}
//           S2{stage A-h1(t+1); read afH; Q(1,0)+Q(1,1); load B(t+1); SBAR}
// FIFO vmcnt ledger: at S1(t) WAITVM2, queue = [S1(t-1):2, S2(t-1):2+8, S1(t):2];
// drain 12 -> A-h0(t) (2 phases old), A-h1(t)+B(t) (1 phase old) resident;
// leave 2 = own stages. B loads issue AFTER last MFMA use of bf regs (in-order
// issue makes reg reuse safe); B is L2-hit (~300cyc) < 1-phase distance.
// LDS reads drop 24->16 insts/wave/tile: LDS port (was co-critical) now < MFMA.
// ---------------------------------------------------------------------------
__global__ __launch_bounds__(512, 2) void gemm_kernel(const f16* __restrict__ Xt,
                                                      const f16* __restrict__ Wt,
                                                      f16* __restrict__ part,
                                                      int nsplit)
{
    __shared__ __align__(16) char ldsA[65536];   // 2 x 32KB A double-buffer

    const int t    = threadIdx.x;
    const int lane = t & 63, wave = t >> 6;

    // bijective XCD swizzle (m204)
    const int nwg = 98 * nsplit;
    const int q = nwg >> 3, r8 = nwg & 7;
    const int xcd = blockIdx.x & 7, idx = blockIdx.x >> 3;
    const int wgid = (xcd < r8 ? xcd * (q + 1) : r8 * (q + 1) + (xcd - r8) * q) + idx;
    const int sk = wgid / 98;
    const int mt = wgid - sk * 98;
    const int m0 = mt * 256;

    // uneven split-K
    const int ntb = 324 / nsplit, rem = 324 - ntb * nsplit;
    const int ksb = sk * ntb + (sk < rem ? sk : rem);
    const int NT  = ntb + (sk < rem ? 1 : 0);

    // ---- A staging source offsets (slot j = i*8+wave, rows j*8+(lane>>3)) ----
    const int csrc = ((lane & 7) ^ (lane >> 3)) * 8;
    int aoff[4];
#pragma unroll
    for (int i = 0; i < 4; ++i) {
        const int r  = (i * 8 + wave) * 8 + (lane >> 3);
        const int ga = (r & 63) + ((r >> 6) & 1) * 128 + (r >> 7) * 64;  // permA
        const int m  = m0 + ga;
        const int b   = m / 784;
        const int rem2 = m - b * 784;
        const int oh  = rem2 / 28;
        const int ow  = rem2 - oh * 28;
        aoff[i] = ((b * 64 + 2 * oh) * 64 + 2 * ow) * 256 + csrc;
    }

    // ---- fragment-read addressing (A from LDS, B from global) ----
    const int wm = wave >> 2, wn = wave & 3;   // 2x4 wave grid, 128x64 each
    int rowA[8];
#pragma unroll
    for (int mf = 0; mf < 8; ++mf) {
        const int g  = wm * 128 + mf * 16 + (lane & 15);
        const int lr = (g & 63) + ((g >> 6) & 1) * 128 + (g >> 7) * 64;  // permA (involution)
        rowA[mf] = lr * 128;
    }
    int csw[2];
    csw[0] = ((lane >> 4) * 16) ^ ((lane & 7) << 4);
    csw[1] = 64 ^ csw[0];
    // B frag base: + ks*16384 per K-step; nf*1024 + h*512 imm-style offsets
    const f16* Bbase = Wt + wn * 4096 + lane * 8;

    f32x4 acc[8][4];
    const f32x4 z = {0.f, 0.f, 0.f, 0.f};
#pragma unroll
    for (int i = 0; i < 8; ++i)
#pragma unroll
        for (int j = 0; j < 4; ++j) acc[i][j] = z;

#define KOFFS_A(KS, AK)                                        \
    {  const int cb_ = (KS) & 3, khw_ = (KS) >> 2;             \
       const int kh_ = khw_ / 9, kw_ = khw_ - kh_ * 9;         \
       AK = (kh_ * 64 + kw_) * 256 + cb_ * 64; }

#define STAGE_A_HALF(H, AK, NB) do {                                               \
    GLD_LDS16(Xt + aoff[2*(H)]   + (AK), ldsA + (NB)*32768 + ((2*(H))*8   + wave)*1024); \
    GLD_LDS16(Xt + aoff[2*(H)+1] + (AK), ldsA + (NB)*32768 + ((2*(H)+1)*8 + wave)*1024); } while(0)

#define LOAD_B(KS) do {                                        \
    const f16* bp_ = Bbase + (long)(KS) * 16384;               \
    bf0[0][0] = *(const f16x8*)(bp_ + 0);                      \
    bf0[0][1] = *(const f16x8*)(bp_ + 512);                    \
    bf0[1][0] = *(const f16x8*)(bp_ + 1024);                   \
    bf0[1][1] = *(const f16x8*)(bp_ + 1536);                   \
    bf1[0][0] = *(const f16x8*)(bp_ + 2048);                   \
    bf1[0][1] = *(const f16x8*)(bp_ + 2560);                   \
    bf1[1][0] = *(const f16x8*)(bp_ + 3072);                   \
    bf1[1][1] = *(const f16x8*)(bp_ + 3584);                   \
} while(0)

#define MFMA_PAIR(MI, NI, A, Bf)                                                        \
    acc[MI][NI] = __builtin_amdgcn_mfma_f32_16x16x32_f16((A)[0], (Bf)[0], acc[MI][NI], 0,0,0); \
    acc[MI][NI] = __builtin_amdgcn_mfma_f32_16x16x32_f16((A)[1], (Bf)[1], acc[MI][NI], 0,0,0);
#define MFMA_Q(MH, NH, BF)                                          \
    MFMA_PAIR((MH)*4+0, (NH)*2+0, af[0], BF[0]) MFMA_PAIR((MH)*4+0, (NH)*2+1, af[0], BF[1]) \
    MFMA_PAIR((MH)*4+1, (NH)*2+0, af[1], BF[0]) MFMA_PAIR((MH)*4+1, (NH)*2+1, af[1], BF[1]) \
    MFMA_PAIR((MH)*4+2, (NH)*2+0, af[2], BF[0]) MFMA_PAIR((MH)*4+2, (NH)*2+1, af[2], BF[1]) \
    MFMA_PAIR((MH)*4+3, (NH)*2+0, af[3], BF[0]) MFMA_PAIR((MH)*4+3, (NH)*2+1, af[3], BF[1])

#define READ_AF(P, MH) do {                                           \
    _Pragma("unroll")                                                 \
    for (int k_ = 0; k_ < 4; ++k_) {                                  \
        af[k_][0] = *(const f16x8*)((P) + rowA[(MH)*4+k_] + csw[0]);  \
        af[k_][1] = *(const f16x8*)((P) + rowA[(MH)*4+k_] + csw[1]);  \
    } } while(0)

    f16x8 af[4][2], bf0[2][2], bf1[2][2];

    // ---- prologue: stage A(0) fully; load B(0) ----
    {
        int ak0;
        KOFFS_A(ksb, ak0);
        STAGE_A_HALF(0, ak0, 0);
        STAGE_A_HALF(1, ak0, 0);
        LOAD_B(ksb);
    }

#pragma unroll 1
    for (int tt = 0; tt < NT; ++tt) {
        const int c = tt & 1, nc = c ^ 1;
        const int ksn = ksb + ((tt + 1 < NT) ? tt + 1 : tt);  // clamp (dup tail)
        int akn;
        KOFFS_A(ksn, akn);
        const char* pA = ldsA + c * 32768;

        // ---- S1: stage A-h0(t+1); VM2 (drains A(t)+B(t)); SBAR; afL; Q(0,*)
        STAGE_A_HALF(0, akn, nc);
        WAITVM2();
        SBAR();
        READ_AF(pA, 0);
        __builtin_amdgcn_s_setprio(1);
        MFMA_Q(0, 0, bf0)
        MFMA_Q(0, 1, bf1)
        __builtin_amdgcn_s_setprio(0);

        // ---- S2: stage A-h1(t+1); afH; Q(1,*); load B(t+1) after last bf use
        STAGE_A_HALF(1, akn, nc);
        READ_AF(pA, 1);
        __builtin_amdgcn_s_setprio(1);
        MFMA_Q(1, 0, bf0)
        MFMA_Q(1, 1, bf1)
        __builtin_amdgcn_s_setprio(0);
        LOAD_B(ksn);
        SBAR();   // all waves done reading buf c -> next tile may stage into it
    }
    WAITVM0();   // drain dangling dup-stage/loads before epilogue

    // ---- epilogue (f16 partials) ----
    f16* base = part + (long)sk * (M_TOTAL * 256);
    const int lrow = (lane >> 4) * 4;
#pragma unroll
    for (int nf = 0; nf < 4; ++nf) {
        const int n = wn * 64 + nf * 16 + (lane & 15);
#pragma unroll
        for (int mf = 0; mf < 8; ++mf) {
            const long mrow = m0 + wm * 128 + mf * 16 + lrow;
            f16* cw = base + mrow * 256 + n;
#pragma unroll
            for (int j = 0; j < 4; ++j) cw[(long)j * 256] = (f16)acc[mf][nf][j];
        }
    }
}

// ---------------------------------------------------------------------------
// Kernel 4: f16 partial-sum + bias + squash + 3-iter routing + acts.
// ---------------------------------------------------------------------------
__global__ __launch_bounds__(256) void routing_kernel(const f16* __restrict__ part,
                                                      const float* __restrict__ bias,
                                                      const float* __restrict__ rb,
                                                      float* __restrict__ out, int nsplit)
{
    const int t   = threadIdx.x;
    const int m   = blockIdx.x * 8 + (t >> 5);
    const int cap = t & 31;
    const int b   = m / 784;
    const int rem = m - b * 784;
    const int oh  = rem / 28;
    const int ow  = rem - oh * 28;

    const float4 b0 = ((const float4*)(bias + cap * 8))[0];
    const float4 b1 = ((const float4*)(bias + cap * 8))[1];
    float v[8] = {b0.x, b0.y, b0.z, b0.w, b1.x, b1.y, b1.z, b1.w};
#pragma unroll 1
    for (int sk = 0; sk < nsplit; ++sk) {
        const f16x8 u = *(const f16x8*)(part + (long)sk * (M_TOTAL * 256) + (long)m * 256 + cap * 8);
#pragma unroll
        for (int j = 0; j < 8; ++j) v[j] += (float)u[j];
    }

    float n2 = 0.f;
#pragma unroll
    for (int j = 0; j < 8; ++j) n2 += v[j] * v[j];
    const float f = (n2 / (1.f + n2)) / sqrtf(n2 + 1e-8f);
    float votes[8];
#pragma unroll
    for (int j = 0; j < 8; ++j) votes[j] = f * v[j];

    const float4* rp = (const float4*)(rb + ((long)(cap * 28 + oh) * 28 + ow) * 8);
    const float4 r0 = rp[0], r1 = rp[1];
    const float rbv[8] = {r0.x, r0.y, r0.z, r0.w, r1.x, r1.y, r1.z, r1.w};

    float logit = 0.f;
    float poses[8];
#pragma unroll 1
    for (int it = 0; it < 3; ++it) {
        float mx = logit;
#pragma unroll
        for (int d = 16; d > 0; d >>= 1) mx = fmaxf(mx, __shfl_xor(mx, d, 32));
        const float e = __expf(logit - mx);
        float se = e;
#pragma unroll
        for (int d = 16; d > 0; d >>= 1) se += __shfl_xor(se, d, 32);
        const float c = e / se;

        float s[8];
        float sn2 = 0.f;
#pragma unroll
        for (int j = 0; j < 8; ++j) { s[j] = c * votes[j] + rbv[j]; sn2 += s[j] * s[j]; }
        const float sf = (sn2 / (1.f + sn2)) / sqrtf(sn2 + 1e-8f);
        float dot = 0.f;
#pragma unroll
        for (int j = 0; j < 8; ++j) { poses[j] = sf * s[j]; dot += votes[j] * poses[j]; }
        logit += dot;
    }

    float pn2 = 0.f;
#pragma unroll
    for (int j = 0; j < 8; ++j) pn2 += poses[j] * poses[j];
    const float act = sqrtf(pn2);

    float* po = out + (((long)(b * 32 + cap) * 28 + oh) * 28 + ow) * 8;
    float4 o0 = {poses[0], poses[1], poses[2], poses[3]};
    float4 o1 = {poses[4], poses[5], poses[6], poses[7]};
    ((float4*)po)[0] = o0;
    ((float4*)po)[1] = o1;
    out[POSE_ELEMS + ((long)(b * 32 + cap) * 28 + oh) * 28 + ow] = act;
}

// ---------------------------------------------------------------------------
extern "C" void kernel_launch(void* const* d_in, const int* in_sizes, int n_in,
                              void* d_out, int out_size, void* d_ws, size_t ws_size,
                              hipStream_t stream)
{
    const float* x      = (const float*)d_in[0];
    const float* conv_w = (const float*)d_in[1];
    const float* conv_b = (const float*)d_in[2];
    const float* rb     = (const float*)d_in[3];
    float* out          = (float*)d_out;

    char* ws = (char*)d_ws;
    f16*   Xt   = (f16*)ws;                                  // 67,108,864 B
    f16*   Wt   = (f16*)(ws + 67108864);                     // 10,616,832 B (frag order)
    const size_t base = 67108864 + 10616832;
    f16* part = (f16*)(ws + base);
    const size_t part_bytes = (size_t)M_TOTAL * 256 * 2;     // 12,845,056 B (f16)

    // nsplit=5: 490 blocks = 95.7% fill, NT=65
    int nsplit = 1;
    if      (ws_size >= base + 5 * part_bytes) nsplit = 5;
    else if (ws_size >= base + 4 * part_bytes) nsplit = 4;
    else if (ws_size >= base + 2 * part_bytes) nsplit = 2;

    xt_kernel<<<dim3(4, 64, 32), 256, 0, stream>>>(x, Xt);
    wt_kernel<<<dim3(1024), 256, 0, stream>>>(conv_w, Wt);
    gemm_kernel<<<dim3(98 * nsplit), dim3(512), 0, stream>>>(Xt, Wt, part, nsplit);
    routing_kernel<<<dim3(3136), 256, 0, stream>>>(part, conv_b, rb, out, nsplit);
}